// Round 1
// baseline (283.225 us; speedup 1.0000x reference)
//
#include <hip/hip_runtime.h>
#include <hip/hip_bf16.h>

// Problem constants (fixed by setup_inputs)
#define NNODES 16384      // B*n = 8*2048
#define KEDGE  16
#define CIN    64
#define HID    64
#define OUTC   128
#define EPS    1e-5f

// Workspace layout (floats):
//   A    : NNODES*390            = 6,389,760
//   y1   : NNODES*64             = 1,048,576   (pre-BN1 node features)
//   t2   : NNODES*128            = 2,097,152   (pre-BN2)
//   st1  : 128  (sum[64], sumsq[64])
//   st2  : 256  (sum[128], sumsq[128])
#define A_OFF   0
#define Y1_OFF  6389760
#define T2_OFF  7438336
#define ST1_OFF 9535488
#define ST2_OFF (ST1_OFF + 128)

// Kernel 1: per-node edge aggregation into Aext rows (390 floats/node).
// One wave (64 lanes) per node; lane = input channel.
__global__ __launch_bounds__(256) void k_edge_agg(
    const float* __restrict__ x, const float* __restrict__ p,
    const int* __restrict__ sid, const int* __restrict__ tid,
    float* __restrict__ A)
{
    int lane = threadIdx.x & 63;
    int wv   = threadIdx.x >> 6;
    int t    = blockIdx.x * 4 + wv;
    int base = t * KEDGE;
    int tn   = tid[base];
    float ptx = p[tn*3+0], pty = p[tn*3+1], ptz = p[tn*3+2];
    float xt  = x[tn*64 + lane];

    int   se[KEDGE];
    float pd[KEDGE];
    float pr = 0.f;
    #pragma unroll
    for (int j = 0; j < KEDGE; ++j) {
        int s = sid[base + j];
        se[j] = s;
        float dx = p[s*3+0] - ptx, dy = p[s*3+1] - pty, dz = p[s*3+2] - ptz;
        float d = sqrtf(dx*dx + dy*dy + dz*dz);
        d = fmaxf(d, 1e-16f);
        pd[j] = d;
        pr = fmaxf(pr, d);
    }
    pr *= 1.1f;
    float wsum = 0.f;
    #pragma unroll
    for (int j = 0; j < KEDGE; ++j) { float w = pr - pd[j]; wsum += w*w; }
    float winv = 1.f / wsum;

    float A0=0,A1=0,A2=0,A3=0,A4=0,A5=0;
    float B0=0,B1=0,B2=0,B3=0,B4=0,B5=0;
    #pragma unroll
    for (int j = 0; j < KEDGE; ++j) {
        int s = se[j];
        float dx = p[s*3+0] - ptx, dy = p[s*3+1] - pty, dz = p[s*3+2] - ptz;
        float invd = 1.f / pd[j];
        float w = pr - pd[j]; w = w*w*winv;
        float c0 = cosf(dx*invd); c0 *= c0;
        float c1 = cosf(dy*invd); c1 *= c1;
        float c2 = cosf(dz*invd); c2 *= c2;
        float e  = x[s*64 + lane] - xt;
        float w0 = w*c0, w1 = w*c1, w2 = w*c2;
        if (dx > 0.f) { A1 += w0*e; B1 += w0; } else { A0 += w0*e; B0 += w0; }
        if (dy > 0.f) { A3 += w1*e; B3 += w1; } else { A2 += w1*e; B2 += w1; }
        if (dz > 0.f) { A5 += w2*e; B5 += w2; } else { A4 += w2*e; B4 += w2; }
    }
    float* Ar = A + (size_t)t * 390;
    Ar[0*64+lane] = A0; Ar[1*64+lane] = A1; Ar[2*64+lane] = A2;
    Ar[3*64+lane] = A3; Ar[4*64+lane] = A4; Ar[5*64+lane] = A5;
    if (lane == 0) {
        Ar[384] = B0; Ar[385] = B1; Ar[386] = B2;
        Ar[387] = B3; Ar[388] = B4; Ar[389] = B5;
    }
}

// Kernel 2: y1 = Aext @ [lins_W ; lins_b]  -> (NNODES, 64)
// One wave handles 4 rows (shares the W column loads).
__global__ __launch_bounds__(256) void k_gemm1(
    const float* __restrict__ A, const float* __restrict__ W,
    const float* __restrict__ bias, float* __restrict__ y1)
{
    int lane = threadIdx.x & 63;
    int wv   = threadIdx.x >> 6;
    int r0   = (blockIdx.x * 4 + wv) * 4;
    const float* A0 = A + (size_t)r0 * 390;
    float acc[4] = {0,0,0,0};
    #pragma unroll 8
    for (int k = 0; k < 384; ++k) {
        float w = W[k*64 + lane];
        #pragma unroll
        for (int i = 0; i < 4; ++i) acc[i] += A0[i*390 + k] * w;
    }
    #pragma unroll
    for (int s = 0; s < 6; ++s) {
        float w = bias[s*64 + lane];
        #pragma unroll
        for (int i = 0; i < 4; ++i) acc[i] += A0[i*390 + 384 + s] * w;
    }
    #pragma unroll
    for (int i = 0; i < 4; ++i) y1[(r0 + i)*64 + lane] = acc[i];
}

// Kernel 3: per-channel sum & sumsq over y1 (64 channels)
__global__ __launch_bounds__(256) void k_stats64(
    const float* __restrict__ y1, float* __restrict__ stats)
{
    int lane = threadIdx.x & 63;
    int wv   = threadIdx.x >> 6;
    int r0   = (blockIdx.x * 4 + wv) * 64;
    float s = 0.f, q = 0.f;
    for (int i = 0; i < 64; ++i) {
        float v = y1[(r0 + i)*64 + lane];
        s += v; q += v*v;
    }
    atomicAdd(&stats[lane], s);
    atomicAdd(&stats[64 + lane], q);
}

// Kernel 4: t2 = x@lin1_W + relu(bn1(y1))@lin2_W + (lin1_b+lin2_b)
// One wave handles 4 rows; lane covers output cols {lane, lane+64}.
__global__ __launch_bounds__(256) void k_fused2(
    const float* __restrict__ x, const int* __restrict__ tid,
    const float* __restrict__ y1, const float* __restrict__ stats1,
    const float* __restrict__ g1, const float* __restrict__ b1,
    const float* __restrict__ W1, const float* __restrict__ bias1,
    const float* __restrict__ W2, const float* __restrict__ bias2,
    float* __restrict__ t2)
{
    int lane = threadIdx.x & 63;
    int wv   = threadIdx.x >> 6;
    int r0   = (blockIdx.x * 4 + wv) * 4;

    float mu  = stats1[lane] * (1.f / NNODES);
    float var = stats1[64 + lane] * (1.f / NNODES) - mu*mu;
    float sc  = rsqrtf(var + EPS) * g1[lane];
    float sh  = b1[lane] - mu*sc;

    float xv[4], zv[4];
    #pragma unroll
    for (int i = 0; i < 4; ++i) {
        int tn = tid[(r0 + i) * KEDGE];
        xv[i] = x[tn*64 + lane];
        float yv = y1[(r0 + i)*64 + lane];
        zv[i] = fmaxf(yv*sc + sh, 0.f);
    }
    float a0[4] = {0,0,0,0}, a1[4] = {0,0,0,0};
    #pragma unroll 4
    for (int k = 0; k < 64; ++k) {
        float w1a = W1[k*128 + lane],      w1b = W1[k*128 + 64 + lane];
        float w2a = W2[k*128 + lane],      w2b = W2[k*128 + 64 + lane];
        #pragma unroll
        for (int i = 0; i < 4; ++i) {
            float xk = __shfl(xv[i], k);
            float zk = __shfl(zv[i], k);
            a0[i] += xk*w1a + zk*w2a;
            a1[i] += xk*w1b + zk*w2b;
        }
    }
    float bb0 = bias1[lane] + bias2[lane];
    float bb1 = bias1[64 + lane] + bias2[64 + lane];
    #pragma unroll
    for (int i = 0; i < 4; ++i) {
        t2[(size_t)(r0 + i)*128 + lane]      = a0[i] + bb0;
        t2[(size_t)(r0 + i)*128 + 64 + lane] = a1[i] + bb1;
    }
}

// Kernel 5: per-channel sum & sumsq over t2 (128 channels)
__global__ __launch_bounds__(256) void k_stats128(
    const float* __restrict__ t2, float* __restrict__ stats)
{
    int c    = threadIdx.x & 127;
    int half = threadIdx.x >> 7;
    int r0   = blockIdx.x * 128 + half * 64;
    float s = 0.f, q = 0.f;
    for (int i = 0; i < 64; ++i) {
        float v = t2[(size_t)(r0 + i)*128 + c];
        s += v; q += v*v;
    }
    atomicAdd(&stats[c], s);
    atomicAdd(&stats[128 + c], q);
}

// Kernel 6: out = relu(bn2(t2))
__global__ __launch_bounds__(256) void k_bn2(
    const float* __restrict__ t2, const float* __restrict__ stats,
    const float* __restrict__ g2, const float* __restrict__ b2,
    float* __restrict__ out)
{
    int idx = blockIdx.x * 256 + threadIdx.x;
    int c   = idx & 127;
    float mu  = stats[c] * (1.f / NNODES);
    float var = stats[128 + c] * (1.f / NNODES) - mu*mu;
    float sc  = rsqrtf(var + EPS) * g2[c];
    float sh  = b2[c] - mu*sc;
    float v = t2[idx];
    out[idx] = fmaxf(v*sc + sh, 0.f);
}

extern "C" void kernel_launch(void* const* d_in, const int* in_sizes, int n_in,
                              void* d_out, int out_size, void* d_ws, size_t ws_size,
                              hipStream_t stream)
{
    const float* x     = (const float*)d_in[0];
    const float* p     = (const float*)d_in[1];
    const int*   sid   = (const int*)d_in[2];
    const int*   tid   = (const int*)d_in[3];
    // d_in[4] = B, d_in[5] = n (scalars, unused — constants hardcoded)
    const float* linsW = (const float*)d_in[6];
    const float* linsB = (const float*)d_in[7];
    const float* W1    = (const float*)d_in[8];
    const float* b1l   = (const float*)d_in[9];
    const float* W2    = (const float*)d_in[10];
    const float* b2l   = (const float*)d_in[11];
    const float* g1    = (const float*)d_in[12];
    const float* bb1   = (const float*)d_in[13];
    const float* g2    = (const float*)d_in[14];
    const float* bb2   = (const float*)d_in[15];

    float* ws  = (float*)d_ws;
    float* A   = ws + A_OFF;
    float* y1  = ws + Y1_OFF;
    float* t2  = ws + T2_OFF;
    float* st1 = ws + ST1_OFF;
    float* st2 = ws + ST2_OFF;

    hipMemsetAsync(st1, 0, (128 + 256) * sizeof(float), stream);

    k_edge_agg<<<NNODES/4, 256, 0, stream>>>(x, p, sid, tid, A);
    k_gemm1  <<<NNODES/16, 256, 0, stream>>>(A, linsW, linsB, y1);
    k_stats64<<<NNODES/256, 256, 0, stream>>>(y1, st1);
    k_fused2 <<<NNODES/16, 256, 0, stream>>>(x, tid, y1, st1, g1, bb1,
                                             W1, b1l, W2, b2l, t2);
    k_stats128<<<NNODES/128, 256, 0, stream>>>(t2, st2);
    k_bn2    <<<(NNODES*OUTC)/256, 256, 0, stream>>>(t2, st2, g2, bb2,
                                                     (float*)d_out);
}